// Round 1
// baseline (2586.499 us; speedup 1.0000x reference)
//
#include <hip/hip_runtime.h>

namespace {
constexpr int FB = 9;         // frequency bands
constexpr int DM = 128;       // d_model
constexpr int NHEADS = 4;
constexpr int DH = 32;
constexpr int E3 = 3 * DM;    // 384
constexpr int FD = FB * DM;   // 1152
constexpr int G  = 4;         // tokens per block
constexpr int NT = 256;
constexpr float LN_EPS = 1e-5f;

__device__ __forceinline__ float dot4f(const float4 a, const float4 w) {
    return a.x * w.x + a.y * w.y + a.z * w.z + a.w * w.w;
}
} // namespace

__global__ __launch_bounds__(NT, 2)
void fba_fused(const float* __restrict__ x,
               const float* __restrict__ band_W,
               const float* __restrict__ band_b,
               const float* __restrict__ freq_pos,
               const float* __restrict__ in_proj_w,
               const float* __restrict__ in_proj_b,
               const float* __restrict__ out_proj_w,
               const float* __restrict__ out_proj_b,
               const float* __restrict__ gate_w,
               const float* __restrict__ gate_b,
               const float* __restrict__ proj1_w,
               const float* __restrict__ proj1_b,
               const float* __restrict__ proj2_w,
               const float* __restrict__ proj2_b,
               const float* __restrict__ ln_g,
               const float* __restrict__ ln_b,
               float* __restrict__ out)
{
    // LDS plan (77.3 KB total -> 2 blocks/CU):
    //   s_tok : tok (phase A/B), then ctx (phase C/D)
    //   s_qkv : qkv (B/C), then per token: flat[0..1152) h[1152..1408)
    //           gate[1408..1536) y[1536..1664)
    __shared__ __align__(16) float s_x[G][16];
    __shared__ __align__(16) float s_tok[G][FD];
    __shared__ __align__(16) float s_qkv[G][FB * E3];
    __shared__ __align__(16) float s_att[G][NHEADS][FB][FB];

    const int t  = threadIdx.x;
    const int n0 = blockIdx.x * G;

    // ---------------- Phase A: stage x, build tok ----------------
    if (t < G * FB) {
        int g = t / FB, f = t - (t / FB) * FB;
        s_x[g][f] = x[(size_t)(n0 + g) * FB + f];
    }
    __syncthreads();
    #pragma unroll
    for (int g = 0; g < G; ++g) {
        for (int r = t; r < FD; r += NT) {
            int f = r >> 7;
            s_tok[g][r] = s_x[g][f] * band_W[r] + band_b[r] + freq_pos[r];
        }
    }
    __syncthreads();

    // ---------------- Phase B: qkv = tok @ in_proj_w^T + b ----------------
    // thread owns weight row e; accumulates over all (g,f); tok reads are
    // wave-uniform LDS broadcasts, weight reads stream per-lane rows via L1.
    for (int e = t; e < E3; e += NT) {
        const float* __restrict__ wrow = in_proj_w + (size_t)e * DM;
        float acc[G][FB];
        #pragma unroll
        for (int g = 0; g < G; ++g)
            #pragma unroll
            for (int f = 0; f < FB; ++f) acc[g][f] = 0.f;
        for (int k = 0; k < DM; k += 4) {
            const float4 w = *(const float4*)(wrow + k);
            #pragma unroll
            for (int g = 0; g < G; ++g)
                #pragma unroll
                for (int f = 0; f < FB; ++f)
                    acc[g][f] += dot4f(*(const float4*)(&s_tok[g][f * DM + k]), w);
        }
        const float b = in_proj_b[e];
        #pragma unroll
        for (int g = 0; g < G; ++g)
            #pragma unroll
            for (int f = 0; f < FB; ++f)
                s_qkv[g][f * E3 + e] = acc[g][f] + b;
    }
    __syncthreads();

    // ---------------- Phase C: attention ----------------
    const float scale = 0.17677669529663687f; // 1/sqrt(32)
    for (int idx = t; idx < G * NHEADS * FB * FB; idx += NT) {
        int g  = idx / (NHEADS * FB * FB);
        int r  = idx - g * (NHEADS * FB * FB);
        int h  = r / (FB * FB);
        int r2 = r - h * (FB * FB);
        int fq = r2 / FB;
        int fk = r2 - fq * FB;
        const float* qp = &s_qkv[g][fq * E3 + h * DH];
        const float* kp = &s_qkv[g][fk * E3 + DM + h * DH];
        float s = 0.f;
        #pragma unroll
        for (int j = 0; j < DH; j += 4)
            s += dot4f(*(const float4*)(qp + j), *(const float4*)(kp + j));
        s_att[g][h][fq][fk] = s * scale;
    }
    __syncthreads();
    if (t < G * NHEADS * FB) {
        int g  = t / (NHEADS * FB);
        int r  = t - g * (NHEADS * FB);
        int h  = r / FB;
        int fq = r - h * FB;
        float* row = &s_att[g][h][fq][0];
        float m = row[0];
        #pragma unroll
        for (int j = 1; j < FB; ++j) m = fmaxf(m, row[j]);
        float e[FB];
        float sum = 0.f;
        #pragma unroll
        for (int j = 0; j < FB; ++j) { e[j] = __expf(row[j] - m); sum += e[j]; }
        float inv = 1.f / sum;
        #pragma unroll
        for (int j = 0; j < FB; ++j) row[j] = e[j] * inv;
    }
    __syncthreads();
    // ctx -> s_tok (tok is dead)
    for (int idx = t; idx < G * FD; idx += NT) {
        int g  = idx / FD;
        int r  = idx - g * FD;
        int fq = r >> 7;
        int i  = r & (DM - 1);
        int h  = i >> 5;
        const float* arow = &s_att[g][h][fq][0];
        float s = 0.f;
        #pragma unroll
        for (int fk = 0; fk < FB; ++fk)
            s += arow[fk] * s_qkv[g][fk * E3 + 2 * DM + i];
        s_tok[g][r] = s;
    }
    __syncthreads();

    // ---------------- Phase D: flat = ctx @ out_proj^T + b ----------------
    // flat stored into s_qkv[g][0..1152) (qkv is dead).
    {
        const int i  = t & (DM - 1);
        const int hf = t >> 7;   // wave-uniform: 0 -> f=0..4, 1 -> f=5..8
        const float* wrow = out_proj_w + (size_t)i * DM;
        const float ob = out_proj_b[i];
        if (hf == 0) {
            float acc[G][5];
            #pragma unroll
            for (int g = 0; g < G; ++g)
                #pragma unroll
                for (int f = 0; f < 5; ++f) acc[g][f] = 0.f;
            for (int k = 0; k < DM; k += 4) {
                const float4 w = *(const float4*)(wrow + k);
                #pragma unroll
                for (int g = 0; g < G; ++g)
                    #pragma unroll
                    for (int f = 0; f < 5; ++f)
                        acc[g][f] += dot4f(*(const float4*)(&s_tok[g][f * DM + k]), w);
            }
            #pragma unroll
            for (int g = 0; g < G; ++g)
                #pragma unroll
                for (int f = 0; f < 5; ++f)
                    s_qkv[g][f * DM + i] = acc[g][f] + ob;
        } else {
            float acc[G][4];
            #pragma unroll
            for (int g = 0; g < G; ++g)
                #pragma unroll
                for (int f = 0; f < 4; ++f) acc[g][f] = 0.f;
            for (int k = 0; k < DM; k += 4) {
                const float4 w = *(const float4*)(wrow + k);
                #pragma unroll
                for (int g = 0; g < G; ++g)
                    #pragma unroll
                    for (int f = 0; f < 4; ++f)
                        acc[g][f] += dot4f(*(const float4*)(&s_tok[g][(5 + f) * DM + k]), w);
            }
            #pragma unroll
            for (int g = 0; g < G; ++g)
                #pragma unroll
                for (int f = 0; f < 4; ++f)
                    s_qkv[g][(5 + f) * DM + i] = acc[g][f] + ob;
        }
    }
    __syncthreads();

    // ---------------- Phase E: gate + proj1 (384 rows of len 1152) ----------------
    for (int r = t; r < E3; r += NT) {
        const bool isg = (r < DM);  // wave-uniform per pass
        const float* __restrict__ wrow =
            isg ? (gate_w + (size_t)r * FD) : (proj1_w + (size_t)(r - DM) * FD);
        float acc[G];
        #pragma unroll
        for (int g = 0; g < G; ++g) acc[g] = 0.f;
        for (int k = 0; k < FD; k += 4) {
            const float4 w = *(const float4*)(wrow + k);
            #pragma unroll
            for (int g = 0; g < G; ++g)
                acc[g] += dot4f(*(const float4*)(&s_qkv[g][k]), w);
        }
        if (isg) {
            const float b = gate_b[r];
            #pragma unroll
            for (int g = 0; g < G; ++g) {
                float v = acc[g] + b;
                s_qkv[g][1408 + r] = 1.f / (1.f + __expf(-v));
            }
        } else {
            const float b = proj1_b[r - DM];
            #pragma unroll
            for (int g = 0; g < G; ++g) {
                float v = acc[g] + b;
                s_qkv[g][1152 + (r - DM)] = 0.5f * v * (1.f + erff(v * 0.70710678118654752f));
            }
        }
    }
    __syncthreads();

    // ---------------- proj2: y = h @ proj2^T + b ----------------
    for (int idx = t; idx < G * DM; idx += NT) {
        int g = idx >> 7;
        int i = idx & (DM - 1);
        const float* __restrict__ wrow = proj2_w + (size_t)i * (2 * DM);
        const float* hp = &s_qkv[g][1152];
        float acc = 0.f;
        #pragma unroll 4
        for (int o = 0; o < 2 * DM; o += 4)
            acc += dot4f(*(const float4*)(hp + o), *(const float4*)(wrow + o));
        s_qkv[g][1536 + i] = acc + proj2_b[i];
    }
    __syncthreads();

    // ---------------- LayerNorm * gate, store (one wave per token) ----------------
    {
        const int g    = t >> 6;
        const int lane = t & 63;
        const float* yp = &s_qkv[g][1536];
        const float y0 = yp[lane], y1 = yp[lane + 64];
        float s = y0 + y1;
        #pragma unroll
        for (int off = 32; off > 0; off >>= 1) s += __shfl_xor(s, off);
        const float mu = s * (1.f / DM);
        const float d0 = y0 - mu, d1 = y1 - mu;
        float v2 = d0 * d0 + d1 * d1;
        #pragma unroll
        for (int off = 32; off > 0; off >>= 1) v2 += __shfl_xor(v2, off);
        const float inv = rsqrtf(v2 * (1.f / DM) + LN_EPS);
        const float* gp = &s_qkv[g][1408];
        const float o0 = (d0 * inv * ln_g[lane]      + ln_b[lane])      * gp[lane];
        const float o1 = (d1 * inv * ln_g[lane + 64] + ln_b[lane + 64]) * gp[lane + 64];
        float* op = out + (size_t)(n0 + g) * DM;
        op[lane]      = o0;
        op[lane + 64] = o1;
    }
}

extern "C" void kernel_launch(void* const* d_in, const int* in_sizes, int n_in,
                              void* d_out, int out_size, void* d_ws, size_t ws_size,
                              hipStream_t stream)
{
    const float* x          = (const float*)d_in[0];
    const float* band_W     = (const float*)d_in[1];
    const float* band_b     = (const float*)d_in[2];
    const float* freq_pos   = (const float*)d_in[3];
    const float* in_proj_w  = (const float*)d_in[4];
    const float* in_proj_b  = (const float*)d_in[5];
    const float* out_proj_w = (const float*)d_in[6];
    const float* out_proj_b = (const float*)d_in[7];
    const float* gate_w     = (const float*)d_in[8];
    const float* gate_b     = (const float*)d_in[9];
    const float* proj1_w    = (const float*)d_in[10];
    const float* proj1_b    = (const float*)d_in[11];
    const float* proj2_w    = (const float*)d_in[12];
    const float* proj2_b    = (const float*)d_in[13];
    const float* ln_g       = (const float*)d_in[14];
    const float* ln_b       = (const float*)d_in[15];
    float* outp = (float*)d_out;

    const int Ntok = in_sizes[0] / FB;   // 32768
    const int nblk = Ntok / G;           // 8192

    hipLaunchKernelGGL(fba_fused, dim3(nblk), dim3(NT), 0, stream,
                       x, band_W, band_b, freq_pos, in_proj_w, in_proj_b,
                       out_proj_w, out_proj_b, gate_w, gate_b,
                       proj1_w, proj1_b, proj2_w, proj2_b, ln_g, ln_b, outp);
}

// Round 2
// 1165.835 us; speedup vs baseline: 2.2186x; 2.2186x over previous
//
#include <hip/hip_runtime.h>

namespace {
constexpr int FB = 9;
constexpr int DM = 128;
constexpr int FD = 1152;     // FB*DM
constexpr int G  = 8;        // tokens per block
constexpr int NT = 384;      // one output row (of 384) per thread in main GEMM
constexpr float LN_EPS = 1e-5f;

// ws layout (float offsets)
constexpr int WS_A   = 0;            // A[9][384]
constexpr int WS_C   = 3456;         // C[9][384]
constexpr int WS_S2  = 6912;         // [4][9][9]
constexpr int WS_S1Q = 7236;
constexpr int WS_S1K = 7560;
constexpr int WS_S0  = 7884;
constexpr int WS_WT4 = 8208;         // fused gate/proj1 weights, [288][384][4] (k-packed)
constexpr int WS_P2T = 450576;       // proj2 transposed packed [64][128][4]
constexpr int WS_BF  = 483344;       // fused bias [384]
} // namespace

// P1: A[f][e] = band_W[f,:]·in_proj_w[e,:];  C[f][e] = (band_b+freq_pos)[f,:]·in_proj_w[e,:] + in_proj_b[e]
__global__ void precompAC(const float* __restrict__ bW, const float* __restrict__ bb,
                          const float* __restrict__ fp, const float* __restrict__ ipw,
                          const float* __restrict__ ipb, float* __restrict__ ws)
{
    __shared__ float sw[128], sc[128];
    const int f = blockIdx.x, t = threadIdx.x;
    if (t < 128) { sw[t] = bW[f * 128 + t]; sc[t] = bb[f * 128 + t] + fp[f * 128 + t]; }
    __syncthreads();
    const float* row = ipw + (size_t)t * 128;
    float a = 0.f, c = 0.f;
    for (int k = 0; k < 128; k += 4) {
        const float4 w = *(const float4*)(row + k);
        a += sw[k]*w.x + sw[k+1]*w.y + sw[k+2]*w.z + sw[k+3]*w.w;
        c += sc[k]*w.x + sc[k+1]*w.y + sc[k+2]*w.z + sc[k+3]*w.w;
    }
    ws[WS_A + f * 384 + t] = a;
    ws[WS_C + f * 384 + t] = c + ipb[t];
}

// P2: score coefficient tensors (include 1/sqrt(32))
__global__ void precompScore(float* __restrict__ ws)
{
    const int t = threadIdx.x;
    if (t >= 324) return;
    const int h = t / 81, r = t % 81, fq = r / 9, fk = r % 9;
    const float* A = ws + WS_A;
    const float* C = ws + WS_C;
    const float* aq = A + fq * 384 + h * 32;
    const float* ak = A + fk * 384 + 128 + h * 32;
    const float* cq = C + fq * 384 + h * 32;
    const float* ck = C + fk * 384 + 128 + h * 32;
    float s2 = 0.f, s1q = 0.f, s1k = 0.f, s0 = 0.f;
    #pragma unroll
    for (int d = 0; d < 32; ++d) {
        s2  += aq[d] * ak[d];
        s1q += aq[d] * ck[d];
        s1k += cq[d] * ak[d];
        s0  += cq[d] * ck[d];
    }
    const float sc = 0.17677669529663687f;
    ws[WS_S2  + t] = s2  * sc;
    ws[WS_S1Q + t] = s1q * sc;
    ws[WS_S1K + t] = s1k * sc;
    ws[WS_S0  + t] = s0  * sc;
}

// P3: fused W'[e, fq, i] = sum_j Win[e, fq*128+j] * out_proj_w[j, i], stored transposed+k-packed
__global__ void precompWT(const float* __restrict__ gw, const float* __restrict__ p1w,
                          const float* __restrict__ opw, float* __restrict__ ws)
{
    __shared__ float sr[128];
    const int bid = blockIdx.x;
    const int e = bid / 9, fq = bid % 9;
    const int i = threadIdx.x;
    const float* Win = (e < 128) ? gw + (size_t)e * FD : p1w + (size_t)(e - 128) * FD;
    sr[i] = Win[fq * 128 + i];
    __syncthreads();
    float acc = 0.f;
    for (int s = 0; s < 128; ++s) acc += sr[s] * opw[s * 128 + i];
    const int k = fq * 128 + i;
    ws[WS_WT4 + (k >> 2) * 1536 + e * 4 + (k & 3)] = acc;
}

// P4: fused bias b'[e] = base_b[e] + sum_m Win[e,m]*out_proj_b[m&127]
__global__ void precompBias(const float* __restrict__ gw, const float* __restrict__ gb,
                            const float* __restrict__ p1w, const float* __restrict__ p1b,
                            const float* __restrict__ opb, float* __restrict__ ws)
{
    const int e = threadIdx.x; // 384
    const float* Win = (e < 128) ? gw + (size_t)e * FD : p1w + (size_t)(e - 128) * FD;
    float acc = (e < 128) ? gb[e] : p1b[e - 128];
    for (int m = 0; m < FD; ++m) acc += Win[m] * opb[m & 127];
    ws[WS_BF + e] = acc;
}

// P5: proj2 transposed packed: p2t4[(o>>2)*512 + i*4 + (o&3)] = proj2_w[i*256+o]
__global__ void precompP2T(const float* __restrict__ p2w, float* __restrict__ ws)
{
    const int idx = blockIdx.x * 256 + threadIdx.x;  // 32768
    const int i = idx >> 8, o = idx & 255;
    ws[WS_P2T + (o >> 2) * 512 + i * 4 + (o & 3)] = p2w[idx];
}

__global__ __launch_bounds__(NT, 3)
void fba_main(const float* __restrict__ x, const float* __restrict__ p2b,
              const float* __restrict__ lng, const float* __restrict__ lnb,
              const float* __restrict__ ws, float* __restrict__ out)
{
    __shared__ __align__(16) float s_x[G][12];
    __shared__ __align__(16) float s_attn[G][324];
    __shared__ __align__(16) float s_w1[G][324];
    __shared__ __align__(16) float s_flat[G][FD];
    __shared__ __align__(16) float s_h[G][256];
    __shared__ __align__(16) float s_gate[G][DM];
    __shared__ __align__(16) float s_y[G][DM];

    const int t  = threadIdx.x;
    const int n0 = blockIdx.x * G;

    if (t < G * FB) { int g = t / FB, f = t - g * FB; s_x[g][f] = x[(size_t)(n0 + g) * FB + f]; }
    __syncthreads();

    // ---- Phase A: scores -> softmax -> attn, w1 = attn*x_k ----
    if (t < G * 36) {
        const int g = t / 36, r = t % 36, h = r / 9, fq = r % 9;
        const int cb = h * 81 + fq * 9;
        const float* s2c  = ws + WS_S2  + cb;
        const float* s1qc = ws + WS_S1Q + cb;
        const float* s1kc = ws + WS_S1K + cb;
        const float* s0c  = ws + WS_S0  + cb;
        const float xq = s_x[g][fq];
        float sc[9];
        float m = -1e30f;
        #pragma unroll
        for (int fk = 0; fk < 9; ++fk) {
            const float xk = s_x[g][fk];
            const float v = (s2c[fk] * xk + s1qc[fk]) * xq + s1kc[fk] * xk + s0c[fk];
            sc[fk] = v;
            m = fmaxf(m, v);
        }
        float sum = 0.f;
        #pragma unroll
        for (int fk = 0; fk < 9; ++fk) { sc[fk] = __expf(sc[fk] - m); sum += sc[fk]; }
        const float inv = 1.f / sum;
        float* ap = &s_attn[g][cb];
        float* wp = &s_w1[g][cb];
        #pragma unroll
        for (int fk = 0; fk < 9; ++fk) {
            const float a = sc[fk] * inv;
            ap[fk] = a;
            wp[fk] = a * s_x[g][fk];
        }
    }
    __syncthreads();

    // ---- Phase B: ctx[fq,i] = sum_fk w1*Av + attn*Cv  -> s_flat ----
    for (int idx = t; idx < FD; idx += NT) {
        const int fq = idx >> 7, i = idx & 127, h = i >> 5;
        const float* Avp = ws + WS_A + 256 + i;
        const float* Cvp = ws + WS_C + 256 + i;
        const int ab = h * 81 + fq * 9;
        float acc[G];
        #pragma unroll
        for (int g = 0; g < G; ++g) acc[g] = 0.f;
        #pragma unroll
        for (int fk = 0; fk < 9; ++fk) {
            const float av = Avp[fk * 384];
            const float cv = Cvp[fk * 384];
            #pragma unroll
            for (int g = 0; g < G; ++g)
                acc[g] += s_w1[g][ab + fk] * av + s_attn[g][ab + fk] * cv;
        }
        #pragma unroll
        for (int g = 0; g < G; ++g) s_flat[g][idx] = acc[g];
    }
    __syncthreads();

    // ---- Phase C: fused gate/proj1 GEMM. thread t owns output row e=t ----
    {
        const int e = t;
        const float* wt = ws + WS_WT4 + e * 4;
        float acc[G];
        #pragma unroll
        for (int g = 0; g < G; ++g) acc[g] = 0.f;
        for (int k4 = 0; k4 < 288; ++k4) {
            const float4 w = *(const float4*)(wt + (size_t)k4 * 1536);
            #pragma unroll
            for (int g = 0; g < G; ++g) {
                const float4 f = *(const float4*)(&s_flat[g][k4 * 4]);
                acc[g] = fmaf(f.x, w.x, acc[g]);
                acc[g] = fmaf(f.y, w.y, acc[g]);
                acc[g] = fmaf(f.z, w.z, acc[g]);
                acc[g] = fmaf(f.w, w.w, acc[g]);
            }
        }
        const float b = ws[WS_BF + e];
        if (e < DM) {
            #pragma unroll
            for (int g = 0; g < G; ++g) {
                const float v = acc[g] + b;
                s_gate[g][e] = 1.f / (1.f + __expf(-v));
            }
        } else {
            const int r = e - DM;
            #pragma unroll
            for (int g = 0; g < G; ++g) {
                const float v = acc[g] + b;
                s_h[g][r] = 0.5f * v * (1.f + erff(v * 0.70710678118654752f));
            }
        }
    }
    __syncthreads();

    // ---- Phase D: proj2 ----
    for (int idx = t; idx < G * DM; idx += NT) {
        const int g = idx >> 7, i = idx & 127;
        const float* wt = ws + WS_P2T + i * 4;
        const float* hp = s_h[g];
        float acc = 0.f;
        #pragma unroll 4
        for (int o4 = 0; o4 < 64; ++o4) {
            const float4 w  = *(const float4*)(wt + o4 * 512);
            const float4 hv = *(const float4*)(hp + o4 * 4);
            acc = fmaf(hv.x, w.x, acc);
            acc = fmaf(hv.y, w.y, acc);
            acc = fmaf(hv.z, w.z, acc);
            acc = fmaf(hv.w, w.w, acc);
        }
        s_y[g][i] = acc + p2b[i];
    }
    __syncthreads();

    // ---- Phase E: LayerNorm * gate, store ----
    {
        const int wid = t >> 6, lane = t & 63;
        for (int rep = 0; rep < 2; ++rep) {
            const int g = wid + rep * 6;
            if (g < G) {
                const float y0 = s_y[g][lane], y1 = s_y[g][lane + 64];
                float s = y0 + y1;
                #pragma unroll
                for (int off = 32; off > 0; off >>= 1) s += __shfl_xor(s, off);
                const float mu = s * (1.f / DM);
                const float d0 = y0 - mu, d1 = y1 - mu;
                float v2 = d0 * d0 + d1 * d1;
                #pragma unroll
                for (int off = 32; off > 0; off >>= 1) v2 += __shfl_xor(v2, off);
                const float inv = rsqrtf(v2 * (1.f / DM) + LN_EPS);
                const float o0 = (d0 * inv * lng[lane]      + lnb[lane])      * s_gate[g][lane];
                const float o1 = (d1 * inv * lng[lane + 64] + lnb[lane + 64]) * s_gate[g][lane + 64];
                float* op = out + (size_t)(n0 + g) * DM;
                op[lane]      = o0;
                op[lane + 64] = o1;
            }
        }
    }
}

extern "C" void kernel_launch(void* const* d_in, const int* in_sizes, int n_in,
                              void* d_out, int out_size, void* d_ws, size_t ws_size,
                              hipStream_t stream)
{
    const float* x          = (const float*)d_in[0];
    const float* band_W     = (const float*)d_in[1];
    const float* band_b     = (const float*)d_in[2];
    const float* freq_pos   = (const float*)d_in[3];
    const float* in_proj_w  = (const float*)d_in[4];
    const float* in_proj_b  = (const float*)d_in[5];
    const float* out_proj_w = (const float*)d_in[6];
    const float* out_proj_b = (const float*)d_in[7];
    const float* gate_w     = (const float*)d_in[8];
    const float* gate_b     = (const float*)d_in[9];
    const float* proj1_w    = (const float*)d_in[10];
    const float* proj1_b    = (const float*)d_in[11];
    const float* proj2_w    = (const float*)d_in[12];
    const float* proj2_b    = (const float*)d_in[13];
    const float* ln_g       = (const float*)d_in[14];
    const float* ln_b       = (const float*)d_in[15];
    float* outp = (float*)d_out;
    float* ws   = (float*)d_ws;

    const int Ntok = in_sizes[0] / FB;   // 32768
    const int nblk = Ntok / G;           // 4096

    hipLaunchKernelGGL(precompAC,    dim3(9),    dim3(384), 0, stream, band_W, band_b, freq_pos, in_proj_w, in_proj_b, ws);
    hipLaunchKernelGGL(precompScore, dim3(1),    dim3(384), 0, stream, ws);
    hipLaunchKernelGGL(precompWT,    dim3(3456), dim3(128), 0, stream, gate_w, proj1_w, out_proj_w, ws);
    hipLaunchKernelGGL(precompBias,  dim3(1),    dim3(384), 0, stream, gate_w, gate_b, proj1_w, proj1_b, out_proj_b, ws);
    hipLaunchKernelGGL(precompP2T,   dim3(128),  dim3(256), 0, stream, proj2_w, ws);
    hipLaunchKernelGGL(fba_main,     dim3(nblk), dim3(NT),  0, stream, x, proj2_b, ln_g, ln_b, ws, outp);
}

// Round 3
// 155.076 us; speedup vs baseline: 16.6790x; 7.5179x over previous
//
#include <hip/hip_runtime.h>

namespace {
constexpr int FB = 9;
constexpr int DM = 128;
constexpr int FD = 1152;
constexpr float LN_EPS = 1e-5f;

typedef __attribute__((ext_vector_type(8))) short short8v;
typedef __attribute__((ext_vector_type(4))) float float4v;

// ---- ws layout ----
// f32 region (float offsets)
constexpr int WSA_F  = 0;      // A[9][384]
constexpr int WSC_F  = 3456;   // C[9][384]
constexpr int COEF_F = 6912;   // [36][40] packed score coeffs
constexpr int BF_F   = 8352;   // fused bias [384]
// byte offsets (bf16 regions)
constexpr int AVCV_B = 35840;  // [4h*2half][64][8] bf16  (8192 B)
constexpr int P2F_B  = 44032;  // [8nt*8ks][64][8] bf16   (65536 B)
constexpr int WT_B   = 109568; // [24nt*36ks][64][8] bf16 (884736 B)

// ---- LDS layout (main kernel), bytes ----
constexpr int L_W1   = 0;      // 27648: [4grp][9fq][768B] w1/attn frags
constexpr int L_ZB   = 27648;  // 256 zeros
constexpr int L_TR   = 27904;  // 4096: per-kstep A-frag staging [4m][1024B]
constexpr int L_GATE = 32000;  // 16384: gate unorm16 [64tok][128]
constexpr int L_HF   = 48384;  // 32768: h frags [4m][8ks][1024B]
constexpr int L_COEF = 48384;  // alias (pre-main only): 5760B
constexpr int L_SX   = 54144;  // alias: 2304B
constexpr int LDS_BYTES = 81152;

__device__ __forceinline__ unsigned short f2bf(float f) {
    unsigned u = __builtin_bit_cast(unsigned, f);
    u += 0x7FFFu + ((u >> 16) & 1u);
    return (unsigned short)(u >> 16);
}
__device__ __forceinline__ float bf2f(unsigned short h) {
    unsigned u = ((unsigned)h) << 16;
    return __builtin_bit_cast(float, u);
}
#define MFMA16x32(a, b, c) __builtin_amdgcn_mfma_f32_16x16x32_bf16(a, b, c, 0, 0, 0)
} // namespace

// ---------------- precompute kernels ----------------
__global__ void precompAC(const float* __restrict__ bW, const float* __restrict__ bb,
                          const float* __restrict__ fp, const float* __restrict__ ipw,
                          const float* __restrict__ ipb, float* __restrict__ ws)
{
    __shared__ float sw[128], sc[128];
    const int f = blockIdx.x, t = threadIdx.x;
    if (t < 128) { sw[t] = bW[f * 128 + t]; sc[t] = bb[f * 128 + t] + fp[f * 128 + t]; }
    __syncthreads();
    const float* row = ipw + (size_t)t * 128;
    float a = 0.f, c = 0.f;
    for (int k = 0; k < 128; k += 4) {
        const float4 w = *(const float4*)(row + k);
        a += sw[k]*w.x + sw[k+1]*w.y + sw[k+2]*w.z + sw[k+3]*w.w;
        c += sc[k]*w.x + sc[k+1]*w.y + sc[k+2]*w.z + sc[k+3]*w.w;
    }
    ws[WSA_F + f * 384 + t] = a;
    ws[WSC_F + f * 384 + t] = c + ipb[t];
}

__global__ void precompScore(float* __restrict__ ws)
{
    const int t = threadIdx.x;
    if (t >= 324) return;
    const int h = t / 81, r = t % 81, fq = r / 9, fk = r % 9;
    const float* A = ws + WSA_F;
    const float* C = ws + WSC_F;
    const float* aq = A + fq * 384 + h * 32;
    const float* ak = A + fk * 384 + 128 + h * 32;
    const float* cq = C + fq * 384 + h * 32;
    const float* ck = C + fk * 384 + 128 + h * 32;
    float s2 = 0.f, s1q = 0.f, s1k = 0.f, s0 = 0.f;
    #pragma unroll
    for (int d = 0; d < 32; ++d) {
        s2  += aq[d] * ak[d];
        s1q += aq[d] * ck[d];
        s1k += cq[d] * ak[d];
        s0  += cq[d] * ck[d];
    }
    const float sc = 0.17677669529663687f;
    float* row = ws + COEF_F + (h * 9 + fq) * 40;
    row[fk]      = s2  * sc;
    row[10 + fk] = s1q * sc;
    row[20 + fk] = s1k * sc;
    row[30 + fk] = s0  * sc;
}

// AvCv bf16 fragment: [hh=(h*2+half)][lane][j]; k=(lane>>4)*8+j; n=lane&15
__global__ void precompAvCv(const float* __restrict__ ws, unsigned short* __restrict__ avcv)
{
    const int id = blockIdx.x * 512 + threadIdx.x;   // 4096
    if (id >= 4096) return;
    const int j = id & 7, lane = (id >> 3) & 63, hh = id >> 9;
    const int h = hh >> 1, half = hh & 1;
    const int i = h * 32 + half * 16 + (lane & 15);
    const int k = (lane >> 4) * 8 + j;
    float v = 0.f;
    if (k < 9)       v = ws[WSA_F + k * 384 + 256 + i];
    else if (k < 18) v = ws[WSC_F + (k - 9) * 384 + 256 + i];
    avcv[id] = f2bf(v);
}

// fused gate/proj1 weights (out_proj folded), bf16 frag layout
__global__ void precompWT(const float* __restrict__ gw, const float* __restrict__ p1w,
                          const float* __restrict__ opw, unsigned short* __restrict__ wt)
{
    __shared__ float sr[128];
    const int bid = blockIdx.x;              // 3456 = 384e * 9fq
    const int e = bid / 9, fq = bid % 9;
    const int i = threadIdx.x;               // 128
    const float* Win = (e < 128) ? gw + (size_t)e * FD : p1w + (size_t)(e - 128) * FD;
    sr[i] = Win[fq * 128 + i];
    __syncthreads();
    float acc = 0.f;
    for (int s = 0; s < 128; ++s) acc += sr[s] * opw[s * 128 + i];
    const int k = fq * 128 + i;
    const int idx = ((e >> 4) * 36 + (k >> 5)) * 512 + ((e & 15) + 16 * ((k >> 3) & 3)) * 8 + (k & 7);
    wt[idx] = f2bf(acc);
}

__global__ void precompBias(const float* __restrict__ gw, const float* __restrict__ gb,
                            const float* __restrict__ p1w, const float* __restrict__ p1b,
                            const float* __restrict__ opb, float* __restrict__ ws)
{
    const int e = threadIdx.x; // 384
    const float* Win = (e < 128) ? gw + (size_t)e * FD : p1w + (size_t)(e - 128) * FD;
    float acc = (e < 128) ? gb[e] : p1b[e - 128];
    for (int m = 0; m < FD; ++m) acc += Win[m] * opb[m & 127];
    ws[BF_F + e] = acc;
}

// proj2^T bf16 frag: [(nt*8+ks)][lane][j]; n=i, k=r
__global__ void precompP2(const float* __restrict__ p2w, unsigned short* __restrict__ p2f)
{
    const int id = blockIdx.x * 512 + threadIdx.x;   // 32768
    const int j = id & 7, lane = (id >> 3) & 63, ks = (id >> 9) & 7, nt = id >> 12;
    const int i = nt * 16 + (lane & 15);
    const int r = ks * 32 + (lane >> 4) * 8 + j;
    p2f[id] = f2bf(p2w[i * 256 + r]);
}

// ---------------- main fused kernel ----------------
__global__ __launch_bounds__(512, 4)
void fba_main(const float* __restrict__ x, const float* __restrict__ p2b,
              const float* __restrict__ lng, const float* __restrict__ lnb,
              const float* __restrict__ wsf,
              const unsigned short* __restrict__ avcv,
              const unsigned short* __restrict__ p2frag,
              const unsigned short* __restrict__ wtfrag,
              float* __restrict__ out)
{
    __shared__ float4 lds4[LDS_BYTES / 16];
    char* lds = (char*)lds4;
    unsigned short* w1frag = (unsigned short*)(lds + L_W1);
    unsigned short* zbp    = (unsigned short*)(lds + L_ZB);
    unsigned short* trb    = (unsigned short*)(lds + L_TR);
    unsigned short* gateb  = (unsigned short*)(lds + L_GATE);
    unsigned short* hfrag  = (unsigned short*)(lds + L_HF);
    float* scoef = (float*)(lds + L_COEF);
    float* sx    = (float*)(lds + L_SX);

    const int t = threadIdx.x, lane = t & 63, wid = t >> 6;
    const int col = lane & 15, rg = lane >> 4;
    const int n0 = blockIdx.x * 64;

    // zero w1frag + zb
    const float4 z4 = {0.f, 0.f, 0.f, 0.f};
    for (int i = t; i < (L_TR / 16); i += 512) lds4[i] = z4;
    // stage coeffs and x
    for (int i = t; i < 1440; i += 512) scoef[i] = wsf[COEF_F + i];
    for (int i = t; i < 576;  i += 512) sx[i] = x[(size_t)n0 * FB + i];
    __syncthreads();

    // ---- Phase A: softmax; scatter w1|attn bf16 frags ----
    for (int id = t; id < 2304; id += 512) {
        const int g = id / 36, r = id - g * 36, h = r / 9, fq = r - (r / 9) * 9;
        const float* cf = scoef + (h * 9 + fq) * 40;
        const float* xg = sx + g * FB;
        const float xq = xg[fq];
        float sc[9];
        float m = -1e30f;
        #pragma unroll
        for (int fk = 0; fk < 9; ++fk) {
            const float xk = xg[fk];
            const float v = (cf[fk] * xk + cf[10 + fk]) * xq + cf[20 + fk] * xk + cf[30 + fk];
            sc[fk] = v;
            m = fmaxf(m, v);
        }
        float sum = 0.f;
        #pragma unroll
        for (int fk = 0; fk < 9; ++fk) { sc[fk] = __expf(sc[fk] - m); sum += sc[fk]; }
        const float inv = 1.f / sum;
        unsigned short* base = w1frag + ((g >> 4) * 9 + fq) * 384;
        const int gl = g & 15;
        #pragma unroll
        for (int fk = 0; fk < 9; ++fk) {
            const float a  = sc[fk] * inv;
            const float w1 = a * xg[fk];
            const int k1 = fk, k2 = 9 + fk;
            base[(gl + 16 * (k1 >> 3)) * 8 + (k1 & 7)] = f2bf(w1);
            base[(gl + 16 * (k2 >> 3)) * 8 + (k2 & 7)] = f2bf(a);
        }
    }
    __syncthreads();

    // ---- main K-loop: ctx-MFMA -> trbuf -> gate/proj1 MFMA ----
    const int nt0 = wid * 3;
    float4v acc[3][4];
    #pragma unroll
    for (int q = 0; q < 3; ++q) {
        const float b = wsf[BF_F + (nt0 + q) * 16 + col];
        #pragma unroll
        for (int m = 0; m < 4; ++m) acc[q][m] = float4v{b, b, b, b};
    }
    const int grp = wid >> 1, half = wid & 1;
    const float4v dz = {0.f, 0.f, 0.f, 0.f};
    const int kl = half * 16 + col;                      // k-offset within 32 of this kstep
    const int troff = grp * 512 + (16 * (kl >> 3)) * 8 + (kl & 7);

    for (int ks = 0; ks < 36; ++ks) {
        const int fq = ks >> 2, h = ks & 3;
        // stage1: ctx MFMA (K=18 in 32)
        const unsigned short* ap = (lane < 48)
            ? (w1frag + (grp * 9 + fq) * 384 + lane * 8)
            : (zbp + col * 8);
        const short8v af = *(const short8v*)ap;
        const short8v bv = *(const short8v*)(avcv + (((h * 2 + half) * 64) + lane) * 8);
        const float4v d = MFMA16x32(af, bv, dz);
        #pragma unroll
        for (int j = 0; j < 4; ++j)
            trb[troff + (rg * 4 + j) * 8] = f2bf(d[j]);
        __syncthreads();
        // stage2: main GEMM step
        short8v am[4];
        #pragma unroll
        for (int m = 0; m < 4; ++m) am[m] = *(const short8v*)(trb + m * 512 + lane * 8);
        #pragma unroll
        for (int q = 0; q < 3; ++q) {
            const short8v bw = *(const short8v*)(wtfrag + (((nt0 + q) * 36 + ks) * 64 + lane) * 8);
            #pragma unroll
            for (int m = 0; m < 4; ++m) acc[q][m] = MFMA16x32(am[m], bw, acc[q][m]);
        }
        __syncthreads();
    }

    // ---- epilogue: gate -> LDS unorm16, h -> hfrag bf16 ----
    #pragma unroll
    for (int q = 0; q < 3; ++q) {
        const int e = (nt0 + q) * 16 + col;
        #pragma unroll
        for (int m = 0; m < 4; ++m) {
            #pragma unroll
            for (int j = 0; j < 4; ++j) {
                const float v = acc[q][m][j];
                const int token = m * 16 + rg * 4 + j;
                if (e < 128) {
                    const float gv = 1.f / (1.f + __expf(-v));
                    gateb[token * 128 + e] = (unsigned short)(gv * 65535.f + 0.5f);
                } else {
                    const int rr = e - 128;
                    const float hv = 0.5f * v * (1.f + erff(v * 0.70710678118654752f));
                    hfrag[m * 4096 + (rr >> 5) * 512 + (rg * 4 + j + 16 * ((rr >> 3) & 3)) * 8 + (rr & 7)] = f2bf(hv);
                }
            }
        }
    }
    __syncthreads();

    // ---- proj2 MFMA + in-register LayerNorm * gate (waves 0..3) ----
    if (wid < 4) {
        const int m = wid;
        float4v y[8];
        float lg[8], lb[8];
        #pragma unroll
        for (int nt = 0; nt < 8; ++nt) {
            const int i = nt * 16 + col;
            const float b = p2b[i];
            y[nt] = float4v{b, b, b, b};
            lg[nt] = lng[i];
            lb[nt] = lnb[i];
        }
        for (int ks = 0; ks < 8; ++ks) {
            const short8v ah = *(const short8v*)(hfrag + m * 4096 + ks * 512 + lane * 8);
            #pragma unroll
            for (int nt = 0; nt < 8; ++nt) {
                const short8v bw = *(const short8v*)(p2frag + ((nt * 8 + ks) * 64 + lane) * 8);
                y[nt] = MFMA16x32(ah, bw, y[nt]);
            }
        }
        #pragma unroll
        for (int j = 0; j < 4; ++j) {
            const int token = m * 16 + rg * 4 + j;
            float s = 0.f;
            #pragma unroll
            for (int nt = 0; nt < 8; ++nt) s += y[nt][j];
            s += __shfl_xor(s, 1); s += __shfl_xor(s, 2);
            s += __shfl_xor(s, 4); s += __shfl_xor(s, 8);
            const float mu = s * (1.f / 128.f);
            float v2 = 0.f;
            #pragma unroll
            for (int nt = 0; nt < 8; ++nt) { const float dd = y[nt][j] - mu; v2 += dd * dd; }
            v2 += __shfl_xor(v2, 1); v2 += __shfl_xor(v2, 2);
            v2 += __shfl_xor(v2, 4); v2 += __shfl_xor(v2, 8);
            const float inv = rsqrtf(v2 * (1.f / 128.f) + LN_EPS);
            float* op = out + (size_t)(n0 + token) * 128;
            #pragma unroll
            for (int nt = 0; nt < 8; ++nt) {
                const int i = nt * 16 + col;
                const float gv = (float)gateb[token * 128 + i] * (1.f / 65535.f);
                op[i] = ((y[nt][j] - mu) * inv * lg[nt] + lb[nt]) * gv;
            }
        }
    }
}

extern "C" void kernel_launch(void* const* d_in, const int* in_sizes, int n_in,
                              void* d_out, int out_size, void* d_ws, size_t ws_size,
                              hipStream_t stream)
{
    const float* x          = (const float*)d_in[0];
    const float* band_W     = (const float*)d_in[1];
    const float* band_b     = (const float*)d_in[2];
    const float* freq_pos   = (const float*)d_in[3];
    const float* in_proj_w  = (const float*)d_in[4];
    const float* in_proj_b  = (const float*)d_in[5];
    const float* out_proj_w = (const float*)d_in[6];
    const float* out_proj_b = (const float*)d_in[7];
    const float* gate_w     = (const float*)d_in[8];
    const float* gate_b     = (const float*)d_in[9];
    const float* proj1_w    = (const float*)d_in[10];
    const float* proj1_b    = (const float*)d_in[11];
    const float* proj2_w    = (const float*)d_in[12];
    const float* proj2_b    = (const float*)d_in[13];
    const float* ln_g       = (const float*)d_in[14];
    const float* ln_b       = (const float*)d_in[15];
    float* outp = (float*)d_out;

    float* wsf = (float*)d_ws;
    unsigned short* avcv = (unsigned short*)((char*)d_ws + AVCV_B);
    unsigned short* p2f  = (unsigned short*)((char*)d_ws + P2F_B);
    unsigned short* wt   = (unsigned short*)((char*)d_ws + WT_B);

    const int Ntok = in_sizes[0] / FB;   // 32768
    const int nblk = Ntok / 64;          // 512

    hipLaunchKernelGGL(precompAC,    dim3(9),    dim3(384), 0, stream, band_W, band_b, freq_pos, in_proj_w, in_proj_b, wsf);
    hipLaunchKernelGGL(precompScore, dim3(1),    dim3(384), 0, stream, wsf);
    hipLaunchKernelGGL(precompAvCv,  dim3(8),    dim3(512), 0, stream, wsf, avcv);
    hipLaunchKernelGGL(precompWT,    dim3(3456), dim3(128), 0, stream, gate_w, proj1_w, out_proj_w, wt);
    hipLaunchKernelGGL(precompBias,  dim3(1),    dim3(384), 0, stream, gate_w, gate_b, proj1_w, proj1_b, out_proj_b, wsf);
    hipLaunchKernelGGL(precompP2,    dim3(64),   dim3(512), 0, stream, proj2_w, p2f);
    hipLaunchKernelGGL(fba_main,     dim3(nblk), dim3(512), 0, stream,
                       x, proj2_b, ln_g, ln_b, wsf, avcv, p2f, wt, outp);
}

// Round 4
// 95.153 us; speedup vs baseline: 27.1824x; 1.6297x over previous
//
#include <hip/hip_runtime.h>

namespace {
constexpr int FB = 9;
constexpr int DM = 128;
constexpr int FD = 1152;
constexpr float LN_EPS = 1e-5f;

typedef __attribute__((ext_vector_type(8))) short short8v;
typedef __attribute__((ext_vector_type(4))) float float4v;

// ---- ws layout ----
// f32 region (float offsets)
constexpr int WSA_F  = 0;      // A[9][384]
constexpr int WSC_F  = 3456;   // C[9][384]
constexpr int COEF_F = 6912;   // [36][40] packed score coeffs
constexpr int BF_F   = 8352;   // fused bias [384]
// byte offsets (bf16 regions)
constexpr int AVCV_B = 35840;  // [4h*2half][64][8] bf16  (8192 B)
constexpr int P2F_B  = 44032;  // [8nt*8ks][64][8] bf16   (65536 B)
constexpr int WT_B   = 109568; // [24nt*36ks][64][8] bf16 (884736 B)

// ---- LDS layout (main kernel), bytes ----
constexpr int L_W1   = 0;      // 27648: [4grp][9fq][768B] w1/attn frags
constexpr int L_ZB   = 27648;  // 256 zeros
constexpr int L_TR   = 27904;  // 4096: per-kstep A-frag staging [4m][1024B]
constexpr int L_GATE = 32000;  // 16384: gate unorm16 [64tok][128]
constexpr int L_HF   = 48384;  // 32768: h frags [4m][8ks][1024B]
constexpr int L_COEF = 48384;  // alias (pre-main only): 5760B
constexpr int L_SX   = 54144;  // alias: 2304B
constexpr int LDS_BYTES = 81152;

// WBP grid split
constexpr int NB_WT   = 1728;  // 2 (e,fq) pairs per block
constexpr int NB_BIAS = 384;
constexpr int NB_P2   = 128;

__device__ __forceinline__ unsigned short f2bf(float f) {
    unsigned u = __builtin_bit_cast(unsigned, f);
    u += 0x7FFFu + ((u >> 16) & 1u);
    return (unsigned short)(u >> 16);
}
#define MFMA16x32(a, b, c) __builtin_amdgcn_mfma_f32_16x16x32_bf16(a, b, c, 0, 0, 0)
} // namespace

// ---------------- P1: A/C ----------------
__global__ void precompAC(const float* __restrict__ bW, const float* __restrict__ bb,
                          const float* __restrict__ fp, const float* __restrict__ ipw,
                          const float* __restrict__ ipb, float* __restrict__ ws)
{
    __shared__ float sw[128], sc[128];
    const int f = blockIdx.x, t = threadIdx.x;
    if (t < 128) { sw[t] = bW[f * 128 + t]; sc[t] = bb[f * 128 + t] + fp[f * 128 + t]; }
    __syncthreads();
    const float* row = ipw + (size_t)t * 128;
    float a = 0.f, c = 0.f;
    for (int k = 0; k < 128; k += 4) {
        const float4 w = *(const float4*)(row + k);
        a += sw[k]*w.x + sw[k+1]*w.y + sw[k+2]*w.z + sw[k+3]*w.w;
        c += sc[k]*w.x + sc[k+1]*w.y + sc[k+2]*w.z + sc[k+3]*w.w;
    }
    ws[WSA_F + f * 384 + t] = a;
    ws[WSC_F + f * 384 + t] = c + ipb[t];
}

// ---------------- P2: score coeffs + AvCv frags (fused) ----------------
__global__ void precompScoreAvCv(const float* __restrict__ ws, unsigned short* __restrict__ avcv,
                                 float* __restrict__ wso)
{
    const int b = blockIdx.x, t = threadIdx.x;
    if (b == 0) {
        if (t >= 324) return;
        const int h = t / 81, r = t % 81, fq = r / 9, fk = r % 9;
        const float* A = ws + WSA_F;
        const float* C = ws + WSC_F;
        const float* aq = A + fq * 384 + h * 32;
        const float* ak = A + fk * 384 + 128 + h * 32;
        const float* cq = C + fq * 384 + h * 32;
        const float* ck = C + fk * 384 + 128 + h * 32;
        float s2 = 0.f, s1q = 0.f, s1k = 0.f, s0 = 0.f;
        #pragma unroll
        for (int d = 0; d < 32; ++d) {
            s2  += aq[d] * ak[d];
            s1q += aq[d] * ck[d];
            s1k += cq[d] * ak[d];
            s0  += cq[d] * ck[d];
        }
        const float sc = 0.17677669529663687f;
        float* row = wso + COEF_F + (h * 9 + fq) * 40;
        row[fk]      = s2  * sc;
        row[10 + fk] = s1q * sc;
        row[20 + fk] = s1k * sc;
        row[30 + fk] = s0  * sc;
    } else {
        const int id = (b - 1) * 512 + t;   // 4096
        if (id >= 4096) return;
        const int j = id & 7, lane = (id >> 3) & 63, hh = id >> 9;
        const int h = hh >> 1, half = hh & 1;
        const int i = h * 32 + half * 16 + (lane & 15);
        const int k = (lane >> 4) * 8 + j;
        float v = 0.f;
        if (k < 9)       v = ws[WSA_F + k * 384 + 256 + i];
        else if (k < 18) v = ws[WSC_F + (k - 9) * 384 + 256 + i];
        avcv[id] = f2bf(v);
    }
}

// ---------------- P3: WT + Bias + P2 fused (256 threads/block) ----------------
__global__ __launch_bounds__(256)
void precompWBP(const float* __restrict__ gw, const float* __restrict__ gb,
                const float* __restrict__ p1w, const float* __restrict__ p1b,
                const float* __restrict__ opw, const float* __restrict__ opb,
                const float* __restrict__ p2w,
                unsigned short* __restrict__ wt, unsigned short* __restrict__ p2f,
                float* __restrict__ ws)
{
    __shared__ float sbuf[2][128];
    const int bid = blockIdx.x, t = threadIdx.x;
    if (bid < NB_WT) {
        // fused gate/proj1 weights with out_proj folded; 2 (e,fq) pairs/block
        const int sub = t >> 7, i = t & 127;
        const int pid = bid * 2 + sub;          // 0..3455
        const int e = pid / 9, fq = pid % 9;
        const float* Win = (e < 128) ? gw + (size_t)e * FD : p1w + (size_t)(e - 128) * FD;
        sbuf[sub][i] = Win[fq * 128 + i];
        __syncthreads();
        float acc = 0.f;
        const float* sr = sbuf[sub];
        for (int s = 0; s < 128; ++s) acc += sr[s] * opw[s * 128 + i];
        const int k = fq * 128 + i;
        const int idx = ((e >> 4) * 36 + (k >> 5)) * 512 + ((e & 15) + 16 * ((k >> 3) & 3)) * 8 + (k & 7);
        wt[idx] = f2bf(acc);
    } else if (bid < NB_WT + NB_BIAS) {
        // fused bias, one e per block, parallel reduce
        const int e = bid - NB_WT;
        const float* Win = (e < 128) ? gw + (size_t)e * FD : p1w + (size_t)(e - 128) * FD;
        float acc = 0.f;
        for (int m = t; m < FD; m += 256) acc += Win[m] * opb[m & 127];
        #pragma unroll
        for (int off = 32; off > 0; off >>= 1) acc += __shfl_xor(acc, off);
        const int lane = t & 63, wid = t >> 6;
        if (lane == 0) sbuf[0][wid] = acc;
        __syncthreads();
        if (t == 0) {
            const float base = (e < 128) ? gb[e] : p1b[e - 128];
            ws[BF_F + e] = base + sbuf[0][0] + sbuf[0][1] + sbuf[0][2] + sbuf[0][3];
        }
    } else {
        // proj2^T bf16 frags
        const int id = (bid - NB_WT - NB_BIAS) * 256 + t;   // 32768
        const int j = id & 7, lane = (id >> 3) & 63, ks = (id >> 9) & 7, nt = id >> 12;
        const int i = nt * 16 + (lane & 15);
        const int r = ks * 32 + (lane >> 4) * 8 + j;
        p2f[id] = f2bf(p2w[i * 256 + r]);
    }
}

// ---------------- main fused kernel ----------------
__global__ __launch_bounds__(512, 2)
void fba_main(const float* __restrict__ x, const float* __restrict__ p2b,
              const float* __restrict__ lng, const float* __restrict__ lnb,
              const float* __restrict__ wsf,
              const unsigned short* __restrict__ avcv,
              const unsigned short* __restrict__ p2frag,
              const unsigned short* __restrict__ wtfrag,
              float* __restrict__ out)
{
    __shared__ float4 lds4[LDS_BYTES / 16];
    char* lds = (char*)lds4;
    unsigned short* w1frag = (unsigned short*)(lds + L_W1);
    unsigned short* zbp    = (unsigned short*)(lds + L_ZB);
    unsigned short* trb    = (unsigned short*)(lds + L_TR);
    unsigned short* gateb  = (unsigned short*)(lds + L_GATE);
    unsigned short* hfrag  = (unsigned short*)(lds + L_HF);
    float* scoef = (float*)(lds + L_COEF);
    float* sx    = (float*)(lds + L_SX);

    const int t = threadIdx.x, lane = t & 63, wid = t >> 6;
    const int col = lane & 15, rg = lane >> 4;
    const int n0 = blockIdx.x * 64;

    // zero w1frag + zb
    const float4 z4 = {0.f, 0.f, 0.f, 0.f};
    for (int i = t; i < (L_TR / 16); i += 512) lds4[i] = z4;
    // stage coeffs and x
    for (int i = t; i < 1440; i += 512) scoef[i] = wsf[COEF_F + i];
    for (int i = t; i < 576;  i += 512) sx[i] = x[(size_t)n0 * FB + i];
    __syncthreads();

    // ---- Phase A: softmax; scatter w1|attn bf16 frags ----
    for (int id = t; id < 2304; id += 512) {
        const int g = id / 36, r = id - g * 36, h = r / 9, fq = r - (r / 9) * 9;
        const float* cf = scoef + (h * 9 + fq) * 40;
        const float* xg = sx + g * FB;
        const float xq = xg[fq];
        float sc[9];
        float m = -1e30f;
        #pragma unroll
        for (int fk = 0; fk < 9; ++fk) {
            const float xk = xg[fk];
            const float v = (cf[fk] * xk + cf[10 + fk]) * xq + cf[20 + fk] * xk + cf[30 + fk];
            sc[fk] = v;
            m = fmaxf(m, v);
        }
        float sum = 0.f;
        #pragma unroll
        for (int fk = 0; fk < 9; ++fk) { sc[fk] = __expf(sc[fk] - m); sum += sc[fk]; }
        const float inv = 1.f / sum;
        unsigned short* base = w1frag + ((g >> 4) * 9 + fq) * 384;
        const int gl = g & 15;
        #pragma unroll
        for (int fk = 0; fk < 9; ++fk) {
            const float a  = sc[fk] * inv;
            const float w1 = a * xg[fk];
            const int k1 = fk, k2 = 9 + fk;
            base[(gl + 16 * (k1 >> 3)) * 8 + (k1 & 7)] = f2bf(w1);
            base[(gl + 16 * (k2 >> 3)) * 8 + (k2 & 7)] = f2bf(a);
        }
    }
    __syncthreads();

    // ---- main K-loop: ctx-MFMA -> trbuf -> gate/proj1 MFMA ----
    const int nt0 = wid * 3;
    float4v acc[3][4];
    #pragma unroll
    for (int q = 0; q < 3; ++q) {
        const float b = wsf[BF_F + (nt0 + q) * 16 + col];
        #pragma unroll
        for (int m = 0; m < 4; ++m) acc[q][m] = float4v{b, b, b, b};
    }
    const int grp = wid >> 1, half = wid & 1;
    const float4v dz = {0.f, 0.f, 0.f, 0.f};
    const int kl = half * 16 + col;
    const int troff = grp * 512 + (16 * (kl >> 3)) * 8 + (kl & 7);

    for (int ks = 0; ks < 36; ++ks) {
        const int fq = ks >> 2, h = ks & 3;
        // stage1: ctx MFMA (K=18 in 32)
        const unsigned short* ap = (lane < 48)
            ? (w1frag + (grp * 9 + fq) * 384 + lane * 8)
            : (zbp + col * 8);
        const short8v af = *(const short8v*)ap;
        const short8v bv = *(const short8v*)(avcv + (((h * 2 + half) * 64) + lane) * 8);
        const float4v d = MFMA16x32(af, bv, dz);
        #pragma unroll
        for (int j = 0; j < 4; ++j)
            trb[troff + (rg * 4 + j) * 8] = f2bf(d[j]);
        __syncthreads();
        // stage2: main GEMM step
        short8v am[4];
        #pragma unroll
        for (int m = 0; m < 4; ++m) am[m] = *(const short8v*)(trb + m * 512 + lane * 8);
        #pragma unroll
        for (int q = 0; q < 3; ++q) {
            const short8v bw = *(const short8v*)(wtfrag + (((nt0 + q) * 36 + ks) * 64 + lane) * 8);
            #pragma unroll
            for (int m = 0; m < 4; ++m) acc[q][m] = MFMA16x32(am[m], bw, acc[q][m]);
        }
        __syncthreads();
    }

    // ---- epilogue: gate -> LDS unorm16, h -> hfrag bf16 ----
    #pragma unroll
    for (int q = 0; q < 3; ++q) {
        const int e = (nt0 + q) * 16 + col;
        #pragma unroll
        for (int m = 0; m < 4; ++m) {
            #pragma unroll
            for (int j = 0; j < 4; ++j) {
                const float v = acc[q][m][j];
                const int token = m * 16 + rg * 4 + j;
                if (e < 128) {
                    const float gv = 1.f / (1.f + __expf(-v));
                    gateb[token * 128 + e] = (unsigned short)(gv * 65535.f + 0.5f);
                } else {
                    const int rr = e - 128;
                    const float hv = 0.5f * v * (1.f + erff(v * 0.70710678118654752f));
                    hfrag[m * 4096 + (rr >> 5) * 512 + (rg * 4 + j + 16 * ((rr >> 3) & 3)) * 8 + (rr & 7)] = f2bf(hv);
                }
            }
        }
    }
    __syncthreads();

    // ---- proj2 MFMA + in-register LayerNorm * gate (waves 0..3) ----
    if (wid < 4) {
        const int m = wid;
        float4v y[8];
        float lg[8], lb[8];
        #pragma unroll
        for (int nt = 0; nt < 8; ++nt) {
            const int i = nt * 16 + col;
            const float b = p2b[i];
            y[nt] = float4v{b, b, b, b};
            lg[nt] = lng[i];
            lb[nt] = lnb[i];
        }
        for (int ks = 0; ks < 8; ++ks) {
            const short8v ah = *(const short8v*)(hfrag + m * 4096 + ks * 512 + lane * 8);
            #pragma unroll
            for (int nt = 0; nt < 8; ++nt) {
                const short8v bw = *(const short8v*)(p2frag + ((nt * 8 + ks) * 64 + lane) * 8);
                y[nt] = MFMA16x32(ah, bw, y[nt]);
            }
        }
        #pragma unroll
        for (int j = 0; j < 4; ++j) {
            const int token = m * 16 + rg * 4 + j;
            float s = 0.f;
            #pragma unroll
            for (int nt = 0; nt < 8; ++nt) s += y[nt][j];
            s += __shfl_xor(s, 1); s += __shfl_xor(s, 2);
            s += __shfl_xor(s, 4); s += __shfl_xor(s, 8);
            const float mu = s * (1.f / 128.f);
            float v2 = 0.f;
            #pragma unroll
            for (int nt = 0; nt < 8; ++nt) { const float dd = y[nt][j] - mu; v2 += dd * dd; }
            v2 += __shfl_xor(v2, 1); v2 += __shfl_xor(v2, 2);
            v2 += __shfl_xor(v2, 4); v2 += __shfl_xor(v2, 8);
            const float inv = rsqrtf(v2 * (1.f / 128.f) + LN_EPS);
            float* op = out + (size_t)(n0 + token) * 128;
            #pragma unroll
            for (int nt = 0; nt < 8; ++nt) {
                const int i = nt * 16 + col;
                const float gv = (float)gateb[token * 128 + i] * (1.f / 65535.f);
                op[i] = ((y[nt][j] - mu) * inv * lg[nt] + lb[nt]) * gv;
            }
        }
    }
}

extern "C" void kernel_launch(void* const* d_in, const int* in_sizes, int n_in,
                              void* d_out, int out_size, void* d_ws, size_t ws_size,
                              hipStream_t stream)
{
    const float* x          = (const float*)d_in[0];
    const float* band_W     = (const float*)d_in[1];
    const float* band_b     = (const float*)d_in[2];
    const float* freq_pos   = (const float*)d_in[3];
    const float* in_proj_w  = (const float*)d_in[4];
    const float* in_proj_b  = (const float*)d_in[5];
    const float* out_proj_w = (const float*)d_in[6];
    const float* out_proj_b = (const float*)d_in[7];
    const float* gate_w     = (const float*)d_in[8];
    const float* gate_b     = (const float*)d_in[9];
    const float* proj1_w    = (const float*)d_in[10];
    const float* proj1_b    = (const float*)d_in[11];
    const float* proj2_w    = (const float*)d_in[12];
    const float* proj2_b    = (const float*)d_in[13];
    const float* ln_g       = (const float*)d_in[14];
    const float* ln_b       = (const float*)d_in[15];
    float* outp = (float*)d_out;

    float* wsf = (float*)d_ws;
    unsigned short* avcv = (unsigned short*)((char*)d_ws + AVCV_B);
    unsigned short* p2f  = (unsigned short*)((char*)d_ws + P2F_B);
    unsigned short* wt   = (unsigned short*)((char*)d_ws + WT_B);

    const int Ntok = in_sizes[0] / FB;   // 32768
    const int nblk = Ntok / 64;          // 512

    hipLaunchKernelGGL(precompAC,       dim3(9),    dim3(384), 0, stream, band_W, band_b, freq_pos, in_proj_w, in_proj_b, wsf);
    hipLaunchKernelGGL(precompScoreAvCv,dim3(9),    dim3(512), 0, stream, wsf, avcv, wsf);
    hipLaunchKernelGGL(precompWBP,      dim3(NB_WT + NB_BIAS + NB_P2), dim3(256), 0, stream,
                       gate_w, gate_b, proj1_w, proj1_b, out_proj_w, out_proj_b, proj2_w, wt, p2f, wsf);
    hipLaunchKernelGGL(fba_main,        dim3(nblk), dim3(512), 0, stream,
                       x, proj2_b, ln_g, ln_b, wsf, avcv, p2f, wt, outp);
}